// Round 2
// baseline (236.607 us; speedup 1.0000x reference)
//
#include <hip/hip_runtime.h>
#include <hip/hip_bf16.h>

namespace {
constexpr int kB = 8;
constexpr int kC = 64;
constexpr int kH = 48;
constexpr int kW = 48;
constexpr int kS = kH * kW;          // 2304
constexpr float kEps = 1.1920929e-07f;
// 0.25 (1/sqrt(head_dim)) * log2(e): lets attention use raw v_exp_f32 (2^x)
constexpr float kQScale = 0.25f * 1.4426950408889634f;
}

typedef __attribute__((ext_vector_type(8))) short short8;   // 8 bf16 (4 VGPR)
typedef __attribute__((ext_vector_type(4))) float f32x4;

// fp32 -> bf16 (round-nearest-even), bit-level
__device__ __forceinline__ short f2bf(float x) {
  unsigned u = __float_as_uint(x);
  u += 0x7fffu + ((u >> 16) & 1u);
  return (short)(u >> 16);
}
__device__ __forceinline__ float bf2f(short s) {
  return __uint_as_float(((unsigned)(unsigned short)s) << 16);
}
__device__ __forceinline__ float fexp2(float x) {
  return __builtin_amdgcn_exp2f(x);   // v_exp_f32 (2^x)
}

// ---------------------------------------------------------------------------
// F1: fused prep (unchanged).
// ---------------------------------------------------------------------------
__global__ __launch_bounds__(256) void fused_prep(
    const float* __restrict__ q, const float* __restrict__ k,
    const float* __restrict__ v, const float* __restrict__ wq,
    const float* __restrict__ wk, const float* __restrict__ conv_w,
    short* __restrict__ qt, short* __restrict__ kt, short* __restrict__ vt,
    short* __restrict__ wqb3, short* __restrict__ wkb3, short* __restrict__ wt3) {
  const int blk = blockIdx.x;
  if (blk < 576) {
    __shared__ float tile[64][65];
    const int zz = blk / 36;         // b*2 + which
    const int bx = blk % 36;
    const int b = zz >> 1;
    const float* src = (zz & 1) ? k : q;
    short* dst = (zz & 1) ? kt : qt;
    const int s0 = bx * 64;
    const int tx = threadIdx.x & 63;
    const int ty = threadIdx.x >> 6;
#pragma unroll
    for (int r = 0; r < 16; ++r) {
      int c = r * 4 + ty;
      tile[c][tx] = src[((size_t)b * kC + c) * kS + s0 + tx];
    }
    __syncthreads();
#pragma unroll
    for (int r = 0; r < 16; ++r) {
      int s = r * 4 + ty;
      dst[((size_t)b * kS + s0 + s) * kC + tx] = f2bf(tile[tx][s]);
    }
  } else if (blk < 1728) {
    int idx = ((blk - 576) * 256 + threadIdx.x) * 4;
    float4 x = *reinterpret_cast<const float4*>(v + idx);
    int2 o;
    o.x = ((int)(unsigned short)f2bf(x.y) << 16) | (unsigned short)f2bf(x.x);
    o.y = ((int)(unsigned short)f2bf(x.w) << 16) | (unsigned short)f2bf(x.z);
    *reinterpret_cast<int2*>(vt + idx) = o;
  } else {
    int idx = (blk - 1728) * 256 + threadIdx.x;
    if (idx < 4096) {
      int j = idx & 7, Lw = (idx >> 3) & 63, slab = idx >> 9;
      int nt = slab & 3, kh = slab >> 2;
      int e = nt * 16 + (Lw & 15), c = kh * 32 + (Lw >> 4) * 8 + j;
      wqb3[idx] = f2bf(wq[e * 64 + c]);
    } else if (idx < 8192) {
      int i2 = idx - 4096;
      int j = i2 & 7, Lw = (i2 >> 3) & 63, slab = i2 >> 9;
      int nt = slab & 3, kh = slab >> 2;
      int e = nt * 16 + (Lw & 15), c = kh * 32 + (Lw >> 4) * 8 + j;
      wkb3[i2] = f2bf(wk[e * 64 + c]);
    } else {
      int i3 = idx - 8192;   // < 36864
      int j = i3 & 7, Lw = (i3 >> 3) & 63, slab = i3 >> 9;   // 0..71
      int nt = slab & 3, kh = (slab >> 2) & 1, tap = slab >> 3;
      int co = nt * 16 + (Lw & 15), ci = kh * 32 + (Lw >> 4) * 8 + j;
      wt3[i3] = f2bf(conv_w[co * 576 + ci * 9 + tap]);
    }
  }
}

// ---------------------------------------------------------------------------
// F2: fused q/k projection GEMMs (unchanged from round 1).
// ---------------------------------------------------------------------------
__global__ __launch_bounds__(256) void fused_qk_gemm(
    const short* __restrict__ qt, const short* __restrict__ kt,
    const short* __restrict__ wt3, const short* __restrict__ wqb3,
    const short* __restrict__ wkb3,
    const float* __restrict__ nq_w, const float* __restrict__ nk_w,
    const float* __restrict__ bq, const float* __restrict__ bk,
    short* __restrict__ qp, short* __restrict__ kp) {
  __shared__ __align__(16) short Qs[164][72];   // q: halo tile / k: 64-row tile
  __shared__ __align__(16) short ln[4][16][80];
  const int blk = blockIdx.x;
  const int t = threadIdx.x;
  const int ws = t >> 6;
  const int L = t & 63;
  const int quad = L >> 4;
  const int l16 = L & 15;
  const short8 zero8 = {0, 0, 0, 0, 0, 0, 0, 0};

  if (blk < 288) {
    // ---- q path ----
    const int b = blk / 36;
    const int S0 = (blk % 36) * 64;
    const int sBase = S0 + ws * 16;
    const int s = sBase + l16;
    const int h = s / kW, w = s % kW;

    const short* qtb = qt + (size_t)b * kS * kC;
#pragma unroll
    for (int it = 0; it < 6; ++it) {
      int idx = it * 256 + t;
      if (idx < 164 * 8) {
        int r = idx >> 3, sg = idx & 7;
        int srow = S0 - 49 + r;
        srow = srow < 0 ? 0 : (srow >= kS ? kS - 1 : srow);
        *reinterpret_cast<int4*>(&Qs[r][sg * 8]) =
            *reinterpret_cast<const int4*>(qtb + (size_t)srow * kC + sg * 8);
      }
    }
    __syncthreads();

    const int baseLocal = ws * 16 + l16 + 49;
    f32x4 acc[4] = {{0.f, 0.f, 0.f, 0.f}, {0.f, 0.f, 0.f, 0.f},
                    {0.f, 0.f, 0.f, 0.f}, {0.f, 0.f, 0.f, 0.f}};
#pragma unroll
    for (int tap = 0; tap < 9; ++tap) {
      const int dh = tap / 3 - 1, dw = tap % 3 - 1;
      const bool valid = (unsigned)(h + dh) < (unsigned)kH &&
                         (unsigned)(w + dw) < (unsigned)kW;
      const int local = baseLocal + dh * kW + dw;
#pragma unroll
      for (int kh = 0; kh < 2; ++kh) {
        short8 af = *reinterpret_cast<const short8*>(&Qs[local][kh * 32 + quad * 8]);
        af = valid ? af : zero8;
        const short* wb = wt3 + ((tap * 2 + kh) * 4) * 512 + L * 8;
#pragma unroll
        for (int nt = 0; nt < 4; ++nt) {
          short8 bf = *reinterpret_cast<const short8*>(wb + nt * 512);  // coalesced
          acc[nt] = __builtin_amdgcn_mfma_f32_16x16x32_bf16(af, bf, acc[nt], 0, 0, 0);
        }
      }
    }
    float rstd[4];
#pragma unroll
    for (int reg = 0; reg < 4; ++reg) {
      float pr = acc[0][reg] * acc[0][reg] + acc[1][reg] * acc[1][reg]
               + acc[2][reg] * acc[2][reg] + acc[3][reg] * acc[3][reg];
      pr += __shfl_xor(pr, 1, 64);
      pr += __shfl_xor(pr, 2, 64);
      pr += __shfl_xor(pr, 4, 64);
      pr += __shfl_xor(pr, 8, 64);
      rstd[reg] = rsqrtf(pr * (1.0f / kC) + kEps);
    }
#pragma unroll
    for (int nt = 0; nt < 4; ++nt) {
      float g = nq_w[nt * 16 + l16];
#pragma unroll
      for (int reg = 0; reg < 4; ++reg) {
        ln[ws][quad * 4 + reg][nt * 16 + l16] = f2bf(acc[nt][reg] * rstd[reg] * g);
      }
    }
    __syncthreads();
    f32x4 acc2[4] = {{0.f, 0.f, 0.f, 0.f}, {0.f, 0.f, 0.f, 0.f},
                     {0.f, 0.f, 0.f, 0.f}, {0.f, 0.f, 0.f, 0.f}};
#pragma unroll
    for (int kh = 0; kh < 2; ++kh) {
      short8 af = *reinterpret_cast<const short8*>(&ln[ws][l16][kh * 32 + quad * 8]);
      const short* wb = wqb3 + (kh * 4) * 512 + L * 8;
#pragma unroll
      for (int nt = 0; nt < 4; ++nt) {
        short8 bf = *reinterpret_cast<const short8*>(wb + nt * 512);   // coalesced
        acc2[nt] = __builtin_amdgcn_mfma_f32_16x16x32_bf16(af, bf, acc2[nt], 0, 0, 0);
      }
    }
#pragma unroll
    for (int nt = 0; nt < 4; ++nt) {
      const int e = nt * 16 + l16;
      float bias = bq[e];
#pragma unroll
      for (int reg = 0; reg < 4; ++reg) {
        qp[((size_t)b * kS + sBase + quad * 4 + reg) * kC + e] =
            f2bf((acc2[nt][reg] + bias) * kQScale);
      }
    }
  } else {
    // ---- k path ----
    const int idx = blk - 288;
    const int b = idx / 36;
    const int S0 = (idx % 36) * 64;
    const int sBase = S0 + ws * 16;

    const short* ktb = kt + ((size_t)b * kS + S0) * kC;
#pragma unroll
    for (int it = 0; it < 2; ++it) {
      int r = it * 32 + (t >> 3), sg = t & 7;
      *reinterpret_cast<int4*>(&Qs[r][sg * 8]) =
          *reinterpret_cast<const int4*>(ktb + (size_t)r * kC + sg * 8);
    }
    __syncthreads();

    short8 af0 = *reinterpret_cast<const short8*>(&Qs[ws * 16 + l16][quad * 8]);
    short8 af1 = *reinterpret_cast<const short8*>(&Qs[ws * 16 + l16][32 + quad * 8]);

    float xs[16];
#pragma unroll
    for (int j = 0; j < 8; ++j) { xs[j] = bf2f(af0[j]); xs[8 + j] = bf2f(af1[j]); }
    float sum = 0.f;
#pragma unroll
    for (int j = 0; j < 16; ++j) sum = fmaf(xs[j], xs[j], sum);
    sum += __shfl_xor(sum, 16, 64);
    sum += __shfl_xor(sum, 32, 64);
    float rstd = rsqrtf(sum * (1.0f / kC) + kEps);

    const float* n0 = nk_w + quad * 8;
#pragma unroll
    for (int j = 0; j < 8; ++j) {
      af0[j] = f2bf(xs[j] * rstd * n0[j]);
      af1[j] = f2bf(xs[8 + j] * rstd * n0[32 + j]);
    }

    f32x4 acc[4] = {{0.f, 0.f, 0.f, 0.f}, {0.f, 0.f, 0.f, 0.f},
                    {0.f, 0.f, 0.f, 0.f}, {0.f, 0.f, 0.f, 0.f}};
#pragma unroll
    for (int nt = 0; nt < 4; ++nt) {
      short8 bf0 = *reinterpret_cast<const short8*>(
          wkb3 + (0 * 4 + nt) * 512 + L * 8);
      short8 bf1 = *reinterpret_cast<const short8*>(
          wkb3 + (1 * 4 + nt) * 512 + L * 8);
      acc[nt] = __builtin_amdgcn_mfma_f32_16x16x32_bf16(af0, bf0, acc[nt], 0, 0, 0);
      acc[nt] = __builtin_amdgcn_mfma_f32_16x16x32_bf16(af1, bf1, acc[nt], 0, 0, 0);
    }
#pragma unroll
    for (int nt = 0; nt < 4; ++nt) {
      const int e = nt * 16 + l16;
      float bias = bk[e];
#pragma unroll
      for (int reg = 0; reg < 4; ++reg) {
        kp[((size_t)b * kS + sBase + quad * 4 + reg) * kC + e] =
            f2bf(acc[nt][reg] + bias);
      }
    }
  }
}

// ---------------------------------------------------------------------------
// K3: flash attention, NO-LDS register-direct version. K/V per batch is
// 288KB+288KB -> L2-resident (FETCH_SIZE ~5MB). LDS staging + per-jt barriers
// were pure overhead (66us with pipes <33% busy). Each wave now loads its
// MFMA A-frags directly global->reg, software-pipelined 1 j-tile ahead; the
// zero-LDS P-transpose K-row permutation moves into the per-lane global
// address (perm j = (l16>>2)*8 + c*4 + (l16&3)). No barriers / no ds ops in
// the main loop; waves fully independent until the epilogue reduce.
// grid 1152: b=blk&7 (XCD-aligned), hp=(blk>>3)&1, i0=(blk>>4)*32.
// 4 waves = (isub, jhalf) as before; epilogue identical (dedicated slab).
// ---------------------------------------------------------------------------
__global__ __launch_bounds__(256, 4) void attn_flash(
    const short* __restrict__ qp, const short* __restrict__ kp,
    const short* __restrict__ vt, float* __restrict__ out) {
  __shared__ float pl[4][16][2];            // [ws][i16][hl]
  __shared__ float Li[32][2];               // 0.25 / l
  __shared__ __align__(16) float slab[16][66];

  const int blk = blockIdx.x;
  const int b = blk & 7;           // low bits -> all of batch b on one XCD (L2 fit)
  const int idx = blk >> 3;        // 0..143
  const int hp = idx & 1;          // head pair: heads 2hp, 2hp+1 (d window hp*32..+31)
  const int i0 = (idx >> 1) * 32;
  const int t = threadIdx.x;
  const int ws = t >> 6;
  const int isub = ws & 1;
  const int jhalf = ws >> 1;
  const int L = t & 63;
  const int quad = L >> 4;
  const int l16 = L & 15;

  const f32x4 zc = {0.f, 0.f, 0.f, 0.f};
  const short8 z8 = {0, 0, 0, 0, 0, 0, 0, 0};

  // Q window (B operand, K=32 = this head pair's d window)
  const short* qrow = qp + ((size_t)b * kS + i0 + isub * 16 + l16) * kC + hp * 32;
  const short8 qw = *reinterpret_cast<const short8*>(qrow + quad * 8);
  const bool lo = quad < 2;
  const short8 qm[2] = {lo ? qw : z8, lo ? z8 : qw};   // local heads 0,1 of the pair

  // Per-lane global addresses.
  // kf[c] lane (l16,quad): source row j = jt*64 + jhalf*32 + (l16>>2)*8 + c*4
  //   + (l16&3)  [the P-transpose permutation], col = hp*32 + quad*8.
  const int permRow = ((l16 >> 2) << 3) | (l16 & 3);
  const short* kbase =
      kp + ((size_t)b * kS + jhalf * 32 + permRow) * kC + hp * 32 + quad * 8;
  // vf[d] lane: row = d*16 + l16 of vt[b] (stride kS), col j = jt*64 + jhalf*32
  //   + quad*8 (unpermuted).
  const short* vbase = vt + ((size_t)b * kC + l16) * kS + jhalf * 32 + quad * 8;

  f32x4 U[2][4];   // [hl][dtile]: lane holds d=dtile*16+quad*4+reg, i=l16
#pragma unroll
  for (int hl = 0; hl < 2; ++hl)
#pragma unroll
    for (int d = 0; d < 4; ++d) U[hl][d] = zc;
  float lh[2] = {0.f, 0.f};

  // prefetch jt = 0
  short8 kn[2], vn[4];
#pragma unroll
  for (int c = 0; c < 2; ++c)
    kn[c] = *reinterpret_cast<const short8*>(kbase + (size_t)c * 4 * kC);
#pragma unroll
  for (int d = 0; d < 4; ++d)
    vn[d] = *reinterpret_cast<const short8*>(vbase + (size_t)d * 16 * kS);

  for (int jt = 0; jt < kS / 64; ++jt) {
    const short8 kf0 = kn[0], kf1 = kn[1];
    const short8 vf0 = vn[0], vf1 = vn[1], vf2 = vn[2], vf3 = vn[3];

    if (jt + 1 < kS / 64) {
      const short* kb2 = kbase + (size_t)(jt + 1) * 64 * kC;
      const short* vb2 = vbase + (size_t)(jt + 1) * 64;
#pragma unroll
      for (int c = 0; c < 2; ++c)
        kn[c] = *reinterpret_cast<const short8*>(kb2 + (size_t)c * 4 * kC);
#pragma unroll
      for (int d = 0; d < 4; ++d)
        vn[d] = *reinterpret_cast<const short8*>(vb2 + (size_t)d * 16 * kS);
    }

#pragma unroll
    for (int hl = 0; hl < 2; ++hl) {
      // chunk c result reg r = e(i=l16, j = quad*8 + c*4 + r)  [permutation]
      f32x4 s0 = __builtin_amdgcn_mfma_f32_16x16x32_bf16(kf0, qm[hl], zc, 0, 0, 0);
      f32x4 s1 = __builtin_amdgcn_mfma_f32_16x16x32_bf16(kf1, qm[hl], zc, 0, 0, 0);
      float e0 = fexp2(s0[0]), e1 = fexp2(s0[1]);
      float e2 = fexp2(s0[2]), e3 = fexp2(s0[3]);
      float f0 = fexp2(s1[0]), f1 = fexp2(s1[1]);
      float f2 = fexp2(s1[2]), f3 = fexp2(s1[3]);
      lh[hl] += ((e0 + e1) + (e2 + e3)) + ((f0 + f1) + (f2 + f3));
      // pack: pf[idx] = e(i=l16, j=quad*8+idx) == PV B-frag, no LDS round-trip
      union { __hip_bfloat162 h2[4]; short8 s8; } cv;
      cv.h2[0] = __float22bfloat162_rn(make_float2(e0, e1));
      cv.h2[1] = __float22bfloat162_rn(make_float2(e2, e3));
      cv.h2[2] = __float22bfloat162_rn(make_float2(f0, f1));
      cv.h2[3] = __float22bfloat162_rn(make_float2(f2, f3));
      U[hl][0] = __builtin_amdgcn_mfma_f32_16x16x32_bf16(vf0, cv.s8, U[hl][0], 0, 0, 0);
      U[hl][1] = __builtin_amdgcn_mfma_f32_16x16x32_bf16(vf1, cv.s8, U[hl][1], 0, 0, 0);
      U[hl][2] = __builtin_amdgcn_mfma_f32_16x16x32_bf16(vf2, cv.s8, U[hl][2], 0, 0, 0);
      U[hl][3] = __builtin_amdgcn_mfma_f32_16x16x32_bf16(vf3, cv.s8, U[hl][3], 0, 0, 0);
    }
  }

  // ---- epilogue (first barrier also re-syncs the free-running waves) ----
#pragma unroll
  for (int hl = 0; hl < 2; ++hl) {
    lh[hl] += __shfl_xor(lh[hl], 16, 64);
    lh[hl] += __shfl_xor(lh[hl], 32, 64);
  }
  if (quad == 0) {
#pragma unroll
    for (int hl = 0; hl < 2; ++hl) pl[ws][l16][hl] = lh[hl];
  }
  __syncthreads();
  if (t < 64) {
    const int i = t >> 1, h2 = t & 1;    // i 0..31 (local sub-row)
    Li[i][h2] = 0.25f / (pl[i >> 4][i & 15][h2] + pl[(i >> 4) + 2][i & 15][h2]);
  }
  __syncthreads();
  float c2[2];
#pragma unroll
  for (int hl = 0; hl < 2; ++hl) c2[hl] = Li[isub * 16 + l16][hl];

  // jhalf-pair reduce, one d-tile per phase
#pragma unroll
  for (int d = 0; d < 4; ++d) {
    if (jhalf == 1) {
#pragma unroll
      for (int hl = 0; hl < 2; ++hl)
#pragma unroll
        for (int reg = 0; reg < 4; ++reg)
          slab[(isub * 2 + hl) * 4 + reg][L] = U[hl][d][reg];
    }
    __syncthreads();
    if (jhalf == 0) {
      float of[4] = {0.f, 0.f, 0.f, 0.f};
#pragma unroll
      for (int hl = 0; hl < 2; ++hl) {
#pragma unroll
        for (int reg = 0; reg < 4; ++reg) {
          float tot = U[hl][d][reg] + slab[(isub * 2 + hl) * 4 + reg][L];
          of[reg] += tot * c2[hl];
        }
      }
      float* op = out + ((size_t)b * kS + i0 + isub * 16 + l16) * kC + d * 16 + quad * 4;
#pragma unroll
      for (int reg = 0; reg < 4; ++reg) atomicAdd(op + reg, of[reg]);
    }
    __syncthreads();
  }
}

// ---------------------------------------------------------------------------
extern "C" void kernel_launch(void* const* d_in, const int* in_sizes, int n_in,
                              void* d_out, int out_size, void* d_ws, size_t ws_size,
                              hipStream_t stream) {
  const float* q      = (const float*)d_in[0];
  const float* k      = (const float*)d_in[1];
  const float* v      = (const float*)d_in[2];
  const float* conv_w = (const float*)d_in[3];
  const float* nq_w   = (const float*)d_in[4];
  const float* nk_w   = (const float*)d_in[5];
  const float* wq     = (const float*)d_in[6];
  const float* bq     = (const float*)d_in[7];
  const float* wk     = (const float*)d_in[8];
  const float* bk     = (const float*)d_in[9];
  float* out = (float*)d_out;

  const size_t N = (size_t)kB * kS * kC;   // 1,179,648
  short* qt   = (short*)d_ws;     // bf16 [b][s][c]
  short* kt   = qt + N;
  short* vt   = kt + N;           // bf16 [b][c][s]
  short* qp   = vt + N;           // bf16 [b][s][64], pre-scaled by 0.25*log2(e)
  short* kp   = qp + N;
  short* wqb3 = kp + N;           // frag-major bf16
  short* wkb3 = wqb3 + 4096;
  short* wt3  = wkb3 + 4096;      // frag-major bf16 [72 slabs][512]

  // head-pair blocks combine via atomicAdd -> zero the output first (capturable)
  hipMemsetAsync(d_out, 0, out_size, stream);

  fused_prep<<<1904, 256, 0, stream>>>(q, k, v, wq, wk, conv_w,
                                       qt, kt, vt, wqb3, wkb3, wt3);
  fused_qk_gemm<<<576, 256, 0, stream>>>(qt, kt, wt3, wqb3, wkb3,
                                         nq_w, nk_w, bq, bk, qp, kp);
  attn_flash<<<1152, 256, 0, stream>>>(qp, kp, vt, out);
}

// Round 3
// 152.211 us; speedup vs baseline: 1.5545x; 1.5545x over previous
//
#include <hip/hip_runtime.h>
#include <hip/hip_bf16.h>

namespace {
constexpr int kB = 8;
constexpr int kC = 64;
constexpr int kH = 48;
constexpr int kW = 48;
constexpr int kS = kH * kW;          // 2304
constexpr float kEps = 1.1920929e-07f;
// 0.25 (1/sqrt(head_dim)) * log2(e): lets attention use raw v_exp_f32 (2^x)
constexpr float kQScale = 0.25f * 1.4426950408889634f;
}

typedef __attribute__((ext_vector_type(8))) short short8;   // 8 bf16 (4 VGPR)
typedef __attribute__((ext_vector_type(4))) float f32x4;

// fp32 -> bf16 (round-nearest-even), bit-level
__device__ __forceinline__ short f2bf(float x) {
  unsigned u = __float_as_uint(x);
  u += 0x7fffu + ((u >> 16) & 1u);
  return (short)(u >> 16);
}
__device__ __forceinline__ float bf2f(short s) {
  return __uint_as_float(((unsigned)(unsigned short)s) << 16);
}
__device__ __forceinline__ float fexp2(float x) {
  return __builtin_amdgcn_exp2f(x);   // v_exp_f32 (2^x)
}

// ---------------------------------------------------------------------------
// F1: fused prep. v-branch now emits FRAGMENT-MAJOR vq so attention's V
// loads are wave-coalesced: vq[b][jseg][d][L][8] holds
// V^T[b][d*16+(L&15)][jseg*32+(L>>4)*8+elem]. Writes coalesced (16B/lane),
// reads scattered 32B (cheap direction). Other branches unchanged.
// grid: 576 transpose + 576 v + 176 weights = 1328.
// ---------------------------------------------------------------------------
__global__ __launch_bounds__(256) void fused_prep(
    const float* __restrict__ q, const float* __restrict__ k,
    const float* __restrict__ v, const float* __restrict__ wq,
    const float* __restrict__ wk, const float* __restrict__ conv_w,
    short* __restrict__ qt, short* __restrict__ kt, short* __restrict__ vq,
    short* __restrict__ wqb3, short* __restrict__ wkb3, short* __restrict__ wt3) {
  const int blk = blockIdx.x;
  if (blk < 576) {
    __shared__ float tile[64][65];
    const int zz = blk / 36;         // b*2 + which
    const int bx = blk % 36;
    const int b = zz >> 1;
    const float* src = (zz & 1) ? k : q;
    short* dst = (zz & 1) ? kt : qt;
    const int s0 = bx * 64;
    const int tx = threadIdx.x & 63;
    const int ty = threadIdx.x >> 6;
#pragma unroll
    for (int r = 0; r < 16; ++r) {
      int c = r * 4 + ty;
      tile[c][tx] = src[((size_t)b * kC + c) * kS + s0 + tx];
    }
    __syncthreads();
#pragma unroll
    for (int r = 0; r < 16; ++r) {
      int s = r * 4 + ty;
      dst[((size_t)b * kS + s0 + s) * kC + tx] = f2bf(tile[tx][s]);
    }
  } else if (blk < 1152) {
    // v -> fragment-major vq. One short8 per thread, coalesced store.
    int g = (blk - 576) * 256 + threadIdx.x;   // short8 index, < 147456
    int bb = g / 18432;                        // 72*4*64 short8 per batch
    int rem = g - bb * 18432;
    int jseg = rem >> 8;                       // 0..71
    int sub = rem & 255;
    int d = sub >> 6;                          // 0..3
    int Lq = sub & 63;                         // layout lane slot
    const float* src = v + ((size_t)(bb * 64 + d * 16 + (Lq & 15))) * kS
                         + jseg * 32 + (Lq >> 4) * 8;
    float4 x0 = *reinterpret_cast<const float4*>(src);
    float4 x1 = *reinterpret_cast<const float4*>(src + 4);
    short8 o;
    o[0] = f2bf(x0.x); o[1] = f2bf(x0.y); o[2] = f2bf(x0.z); o[3] = f2bf(x0.w);
    o[4] = f2bf(x1.x); o[5] = f2bf(x1.y); o[6] = f2bf(x1.z); o[7] = f2bf(x1.w);
    *reinterpret_cast<short8*>(vq + (size_t)g * 8) = o;
  } else {
    int idx = (blk - 1152) * 256 + threadIdx.x;
    if (idx < 4096) {
      int j = idx & 7, Lw = (idx >> 3) & 63, slab = idx >> 9;
      int nt = slab & 3, kh = slab >> 2;
      int e = nt * 16 + (Lw & 15), c = kh * 32 + (Lw >> 4) * 8 + j;
      wqb3[idx] = f2bf(wq[e * 64 + c]);
    } else if (idx < 8192) {
      int i2 = idx - 4096;
      int j = i2 & 7, Lw = (i2 >> 3) & 63, slab = i2 >> 9;
      int nt = slab & 3, kh = slab >> 2;
      int e = nt * 16 + (Lw & 15), c = kh * 32 + (Lw >> 4) * 8 + j;
      wkb3[i2] = f2bf(wk[e * 64 + c]);
    } else {
      int i3 = idx - 8192;   // < 36864
      int j = i3 & 7, Lw = (i3 >> 3) & 63, slab = i3 >> 9;   // 0..71
      int nt = slab & 3, kh = (slab >> 2) & 1, tap = slab >> 3;
      int co = nt * 16 + (Lw & 15), ci = kh * 32 + (Lw >> 4) * 8 + j;
      wt3[i3] = f2bf(conv_w[co * 576 + ci * 9 + tap]);
    }
  }
}

// ---------------------------------------------------------------------------
// F2: fused q/k projection GEMMs. k-path epilogue now stores FRAGMENT-MAJOR
// kq[b][jseg][hp][c][L][8]: element (s,e) lands at jseg=s>>5, jrow=s&31,
// c=(jrow>>2)&1, l16'=((jrow>>3)<<2)|(jrow&3), hp=e>>5, quad'=(e&31)>>3,
// elem=e&7 -- so attention's K A-frag load is base + L*16B (coalesced).
// Identical fragment CONTENT to the round-1 LDS permutation. q path unchanged.
// ---------------------------------------------------------------------------
__global__ __launch_bounds__(256) void fused_qk_gemm(
    const short* __restrict__ qt, const short* __restrict__ kt,
    const short* __restrict__ wt3, const short* __restrict__ wqb3,
    const short* __restrict__ wkb3,
    const float* __restrict__ nq_w, const float* __restrict__ nk_w,
    const float* __restrict__ bq, const float* __restrict__ bk,
    short* __restrict__ qp, short* __restrict__ kq) {
  __shared__ __align__(16) short Qs[164][72];   // q: halo tile / k: 64-row tile
  __shared__ __align__(16) short ln[4][16][80];
  const int blk = blockIdx.x;
  const int t = threadIdx.x;
  const int ws = t >> 6;
  const int L = t & 63;
  const int quad = L >> 4;
  const int l16 = L & 15;
  const short8 zero8 = {0, 0, 0, 0, 0, 0, 0, 0};

  if (blk < 288) {
    // ---- q path ----
    const int b = blk / 36;
    const int S0 = (blk % 36) * 64;
    const int sBase = S0 + ws * 16;
    const int s = sBase + l16;
    const int h = s / kW, w = s % kW;

    const short* qtb = qt + (size_t)b * kS * kC;
#pragma unroll
    for (int it = 0; it < 6; ++it) {
      int idx = it * 256 + t;
      if (idx < 164 * 8) {
        int r = idx >> 3, sg = idx & 7;
        int srow = S0 - 49 + r;
        srow = srow < 0 ? 0 : (srow >= kS ? kS - 1 : srow);
        *reinterpret_cast<int4*>(&Qs[r][sg * 8]) =
            *reinterpret_cast<const int4*>(qtb + (size_t)srow * kC + sg * 8);
      }
    }
    __syncthreads();

    const int baseLocal = ws * 16 + l16 + 49;
    f32x4 acc[4] = {{0.f, 0.f, 0.f, 0.f}, {0.f, 0.f, 0.f, 0.f},
                    {0.f, 0.f, 0.f, 0.f}, {0.f, 0.f, 0.f, 0.f}};
#pragma unroll
    for (int tap = 0; tap < 9; ++tap) {
      const int dh = tap / 3 - 1, dw = tap % 3 - 1;
      const bool valid = (unsigned)(h + dh) < (unsigned)kH &&
                         (unsigned)(w + dw) < (unsigned)kW;
      const int local = baseLocal + dh * kW + dw;
#pragma unroll
      for (int kh = 0; kh < 2; ++kh) {
        short8 af = *reinterpret_cast<const short8*>(&Qs[local][kh * 32 + quad * 8]);
        af = valid ? af : zero8;
        const short* wb = wt3 + ((tap * 2 + kh) * 4) * 512 + L * 8;
#pragma unroll
        for (int nt = 0; nt < 4; ++nt) {
          short8 bf = *reinterpret_cast<const short8*>(wb + nt * 512);  // coalesced
          acc[nt] = __builtin_amdgcn_mfma_f32_16x16x32_bf16(af, bf, acc[nt], 0, 0, 0);
        }
      }
    }
    float rstd[4];
#pragma unroll
    for (int reg = 0; reg < 4; ++reg) {
      float pr = acc[0][reg] * acc[0][reg] + acc[1][reg] * acc[1][reg]
               + acc[2][reg] * acc[2][reg] + acc[3][reg] * acc[3][reg];
      pr += __shfl_xor(pr, 1, 64);
      pr += __shfl_xor(pr, 2, 64);
      pr += __shfl_xor(pr, 4, 64);
      pr += __shfl_xor(pr, 8, 64);
      rstd[reg] = rsqrtf(pr * (1.0f / kC) + kEps);
    }
#pragma unroll
    for (int nt = 0; nt < 4; ++nt) {
      float g = nq_w[nt * 16 + l16];
#pragma unroll
      for (int reg = 0; reg < 4; ++reg) {
        ln[ws][quad * 4 + reg][nt * 16 + l16] = f2bf(acc[nt][reg] * rstd[reg] * g);
      }
    }
    __syncthreads();
    f32x4 acc2[4] = {{0.f, 0.f, 0.f, 0.f}, {0.f, 0.f, 0.f, 0.f},
                     {0.f, 0.f, 0.f, 0.f}, {0.f, 0.f, 0.f, 0.f}};
#pragma unroll
    for (int kh = 0; kh < 2; ++kh) {
      short8 af = *reinterpret_cast<const short8*>(&ln[ws][l16][kh * 32 + quad * 8]);
      const short* wb = wqb3 + (kh * 4) * 512 + L * 8;
#pragma unroll
      for (int nt = 0; nt < 4; ++nt) {
        short8 bf = *reinterpret_cast<const short8*>(wb + nt * 512);   // coalesced
        acc2[nt] = __builtin_amdgcn_mfma_f32_16x16x32_bf16(af, bf, acc2[nt], 0, 0, 0);
      }
    }
#pragma unroll
    for (int nt = 0; nt < 4; ++nt) {
      const int e = nt * 16 + l16;
      float bias = bq[e];
#pragma unroll
      for (int reg = 0; reg < 4; ++reg) {
        qp[((size_t)b * kS + sBase + quad * 4 + reg) * kC + e] =
            f2bf((acc2[nt][reg] + bias) * kQScale);
      }
    }
  } else {
    // ---- k path ----
    const int idx = blk - 288;
    const int b = idx / 36;
    const int S0 = (idx % 36) * 64;
    const int sBase = S0 + ws * 16;

    const short* ktb = kt + ((size_t)b * kS + S0) * kC;
#pragma unroll
    for (int it = 0; it < 2; ++it) {
      int r = it * 32 + (t >> 3), sg = t & 7;
      *reinterpret_cast<int4*>(&Qs[r][sg * 8]) =
          *reinterpret_cast<const int4*>(ktb + (size_t)r * kC + sg * 8);
    }
    __syncthreads();

    short8 af0 = *reinterpret_cast<const short8*>(&Qs[ws * 16 + l16][quad * 8]);
    short8 af1 = *reinterpret_cast<const short8*>(&Qs[ws * 16 + l16][32 + quad * 8]);

    float xs[16];
#pragma unroll
    for (int j = 0; j < 8; ++j) { xs[j] = bf2f(af0[j]); xs[8 + j] = bf2f(af1[j]); }
    float sum = 0.f;
#pragma unroll
    for (int j = 0; j < 16; ++j) sum = fmaf(xs[j], xs[j], sum);
    sum += __shfl_xor(sum, 16, 64);
    sum += __shfl_xor(sum, 32, 64);
    float rstd = rsqrtf(sum * (1.0f / kC) + kEps);

    const float* n0 = nk_w + quad * 8;
#pragma unroll
    for (int j = 0; j < 8; ++j) {
      af0[j] = f2bf(xs[j] * rstd * n0[j]);
      af1[j] = f2bf(xs[8 + j] * rstd * n0[32 + j]);
    }

    f32x4 acc[4] = {{0.f, 0.f, 0.f, 0.f}, {0.f, 0.f, 0.f, 0.f},
                    {0.f, 0.f, 0.f, 0.f}, {0.f, 0.f, 0.f, 0.f}};
#pragma unroll
    for (int nt = 0; nt < 4; ++nt) {
      short8 bf0 = *reinterpret_cast<const short8*>(
          wkb3 + (0 * 4 + nt) * 512 + L * 8);
      short8 bf1 = *reinterpret_cast<const short8*>(
          wkb3 + (1 * 4 + nt) * 512 + L * 8);
      acc[nt] = __builtin_amdgcn_mfma_f32_16x16x32_bf16(af0, bf0, acc[nt], 0, 0, 0);
      acc[nt] = __builtin_amdgcn_mfma_f32_16x16x32_bf16(af1, bf1, acc[nt], 0, 0, 0);
    }
    // fragment-major store (see header comment)
    short* kqb = kq + (size_t)b * 147456;   // 72 * 2048 shorts per batch
#pragma unroll
    for (int nt = 0; nt < 4; ++nt) {
      const int e = nt * 16 + l16;
      const int hp = nt >> 1;
      const int quadp = ((nt & 1) << 1) | (l16 >> 3);
      const int elem = l16 & 7;
      float bias = bk[e];
#pragma unroll
      for (int reg = 0; reg < 4; ++reg) {
        int s = sBase + quad * 4 + reg;
        int jseg = s >> 5, jrow = s & 31;
        int c = (jrow >> 2) & 1;
        int l16p = ((jrow >> 3) << 2) | (jrow & 3);
        kqb[((((size_t)jseg * 2 + hp) * 2 + c) * 64 + quadp * 16 + l16p) * 8 + elem] =
            f2bf(acc[nt][reg] + bias);
      }
    }
  }
}

// ---------------------------------------------------------------------------
// K3: flash attention, register-direct with FRAGMENT-MAJOR operands.
// Round-2's failure was uncoalesced per-lane loads (16 transactions/load);
// kq/vq layouts make every main-loop load base + L*16B: one coalesced
// dwordx4 per wave from L2. Zero LDS in main loop, zero barriers, waves
// independent until epilogue. Fragment contents identical to rounds 1/2.
// grid 1152: b=blk&7 (XCD-aligned), hp=(blk>>3)&1, i0=(blk>>4)*32.
// ---------------------------------------------------------------------------
__global__ __launch_bounds__(256, 4) void attn_flash(
    const short* __restrict__ qp, const short* __restrict__ kq,
    const short* __restrict__ vq, float* __restrict__ out) {
  __shared__ float pl[4][16][2];            // [ws][i16][hl]
  __shared__ float Li[32][2];               // 0.25 / l
  __shared__ __align__(16) float slab[16][66];

  const int blk = blockIdx.x;
  const int b = blk & 7;           // low bits -> all of batch b on one XCD (L2 fit)
  const int idx = blk >> 3;        // 0..143
  const int hp = idx & 1;          // head pair: heads 2hp, 2hp+1
  const int i0 = (idx >> 1) * 32;
  const int t = threadIdx.x;
  const int ws = t >> 6;
  const int isub = ws & 1;
  const int jhalf = ws >> 1;
  const int L = t & 63;
  const int quad = L >> 4;
  const int l16 = L & 15;

  const f32x4 zc = {0.f, 0.f, 0.f, 0.f};
  const short8 z8 = {0, 0, 0, 0, 0, 0, 0, 0};

  // Q window (B operand, K=32 = this head pair's d window)
  const short* qrow = qp + ((size_t)b * kS + i0 + isub * 16 + l16) * kC + hp * 32;
  const short8 qw = *reinterpret_cast<const short8*>(qrow + quad * 8);
  const bool lo = quad < 2;
  const short8 qm[2] = {lo ? qw : z8, lo ? z8 : qw};   // local heads 0,1 of the pair

  // Fragment-major bases: every load below is base + (lane)*16B, coalesced.
  // kq[b][jseg][hp][c][L][8]: jseg = jt*2 + jhalf, c offset = c*512 shorts,
  // jt stride = 2 jseg = 4096 shorts. vq[b][jseg][d][L][8]: d offset = d*512,
  // jt stride = 4096 shorts.
  const short* kbase =
      kq + (((size_t)(b * 72 + jhalf) * 2 + hp) * 2 * 64 + L) * 8;
  const short* vbase = vq + ((size_t)(b * 72 + jhalf) * 4 * 64 + L) * 8;

  f32x4 U[2][4];   // [hl][dtile]: lane holds d=dtile*16+quad*4+reg, i=l16
#pragma unroll
  for (int hl = 0; hl < 2; ++hl)
#pragma unroll
    for (int d = 0; d < 4; ++d) U[hl][d] = zc;
  float lh[2] = {0.f, 0.f};

  // prefetch jt = 0
  short8 kn[2], vn[4];
#pragma unroll
  for (int c = 0; c < 2; ++c)
    kn[c] = *reinterpret_cast<const short8*>(kbase + c * 512);
#pragma unroll
  for (int d = 0; d < 4; ++d)
    vn[d] = *reinterpret_cast<const short8*>(vbase + d * 512);

  for (int jt = 0; jt < kS / 64; ++jt) {
    const short8 kf0 = kn[0], kf1 = kn[1];
    const short8 vf0 = vn[0], vf1 = vn[1], vf2 = vn[2], vf3 = vn[3];

    if (jt + 1 < kS / 64) {
      const short* kb2 = kbase + (size_t)(jt + 1) * 4096;
      const short* vb2 = vbase + (size_t)(jt + 1) * 4096;
#pragma unroll
      for (int c = 0; c < 2; ++c)
        kn[c] = *reinterpret_cast<const short8*>(kb2 + c * 512);
#pragma unroll
      for (int d = 0; d < 4; ++d)
        vn[d] = *reinterpret_cast<const short8*>(vb2 + d * 512);
    }

#pragma unroll
    for (int hl = 0; hl < 2; ++hl) {
      // chunk c result reg r = e(i=l16, j = quad*8 + c*4 + r)  [permutation]
      f32x4 s0 = __builtin_amdgcn_mfma_f32_16x16x32_bf16(kf0, qm[hl], zc, 0, 0, 0);
      f32x4 s1 = __builtin_amdgcn_mfma_f32_16x16x32_bf16(kf1, qm[hl], zc, 0, 0, 0);
      float e0 = fexp2(s0[0]), e1 = fexp2(s0[1]);
      float e2 = fexp2(s0[2]), e3 = fexp2(s0[3]);
      float f0 = fexp2(s1[0]), f1 = fexp2(s1[1]);
      float f2 = fexp2(s1[2]), f3 = fexp2(s1[3]);
      lh[hl] += ((e0 + e1) + (e2 + e3)) + ((f0 + f1) + (f2 + f3));
      // pack: pf[idx] = e(i=l16, j=quad*8+idx) == PV B-frag, no LDS round-trip
      union { __hip_bfloat162 h2[4]; short8 s8; } cv;
      cv.h2[0] = __float22bfloat162_rn(make_float2(e0, e1));
      cv.h2[1] = __float22bfloat162_rn(make_float2(e2, e3));
      cv.h2[2] = __float22bfloat162_rn(make_float2(f0, f1));
      cv.h2[3] = __float22bfloat162_rn(make_float2(f2, f3));
      U[hl][0] = __builtin_amdgcn_mfma_f32_16x16x32_bf16(vf0, cv.s8, U[hl][0], 0, 0, 0);
      U[hl][1] = __builtin_amdgcn_mfma_f32_16x16x32_bf16(vf1, cv.s8, U[hl][1], 0, 0, 0);
      U[hl][2] = __builtin_amdgcn_mfma_f32_16x16x32_bf16(vf2, cv.s8, U[hl][2], 0, 0, 0);
      U[hl][3] = __builtin_amdgcn_mfma_f32_16x16x32_bf16(vf3, cv.s8, U[hl][3], 0, 0, 0);
    }
  }

  // ---- epilogue (first barrier re-syncs the free-running waves) ----
#pragma unroll
  for (int hl = 0; hl < 2; ++hl) {
    lh[hl] += __shfl_xor(lh[hl], 16, 64);
    lh[hl] += __shfl_xor(lh[hl], 32, 64);
  }
  if (quad == 0) {
#pragma unroll
    for (int hl = 0; hl < 2; ++hl) pl[ws][l16][hl] = lh[hl];
  }
  __syncthreads();
  if (t < 64) {
    const int i = t >> 1, h2 = t & 1;    // i 0..31 (local sub-row)
    Li[i][h2] = 0.25f / (pl[i >> 4][i & 15][h2] + pl[(i >> 4) + 2][i & 15][h2]);
  }
  __syncthreads();
  float c2[2];
#pragma unroll
  for (int hl = 0; hl < 2; ++hl) c2[hl] = Li[isub * 16 + l16][hl];

  // jhalf-pair reduce, one d-tile per phase
#pragma unroll
  for (int d = 0; d < 4; ++d) {
    if (jhalf == 1) {
#pragma unroll
      for (int hl = 0; hl < 2; ++hl)
#pragma unroll
        for (int reg = 0; reg < 4; ++reg)
          slab[(isub * 2 + hl) * 4 + reg][L] = U[hl][d][reg];
    }
    __syncthreads();
    if (jhalf == 0) {
      float of[4] = {0.f, 0.f, 0.f, 0.f};
#pragma unroll
      for (int hl = 0; hl < 2; ++hl) {
#pragma unroll
        for (int reg = 0; reg < 4; ++reg) {
          float tot = U[hl][d][reg] + slab[(isub * 2 + hl) * 4 + reg][L];
          of[reg] += tot * c2[hl];
        }
      }
      float* op = out + ((size_t)b * kS + i0 + isub * 16 + l16) * kC + d * 16 + quad * 4;
#pragma unroll
      for (int reg = 0; reg < 4; ++reg) atomicAdd(op + reg, of[reg]);
    }
    __syncthreads();
  }
}

// ---------------------------------------------------------------------------
extern "C" void kernel_launch(void* const* d_in, const int* in_sizes, int n_in,
                              void* d_out, int out_size, void* d_ws, size_t ws_size,
                              hipStream_t stream) {
  const float* q      = (const float*)d_in[0];
  const float* k      = (const float*)d_in[1];
  const float* v      = (const float*)d_in[2];
  const float* conv_w = (const float*)d_in[3];
  const float* nq_w   = (const float*)d_in[4];
  const float* nk_w   = (const float*)d_in[5];
  const float* wq     = (const float*)d_in[6];
  const float* bq     = (const float*)d_in[7];
  const float* wk     = (const float*)d_in[8];
  const float* bk     = (const float*)d_in[9];
  float* out = (float*)d_out;

  const size_t N = (size_t)kB * kS * kC;   // 1,179,648
  short* qt   = (short*)d_ws;     // bf16 [b][s][c]
  short* kt   = qt + N;
  short* vq   = kt + N;           // bf16 fragment-major V
  short* qp   = vq + N;           // bf16 [b][s][64], pre-scaled by 0.25*log2(e)
  short* kq   = qp + N;           // bf16 fragment-major K-proj
  short* wqb3 = kq + N;           // frag-major bf16
  short* wkb3 = wqb3 + 4096;
  short* wt3  = wkb3 + 4096;      // frag-major bf16 [72 slabs][512]

  // head-pair blocks combine via atomicAdd -> zero the output first (capturable)
  hipMemsetAsync(d_out, 0, out_size, stream);

  fused_prep<<<1328, 256, 0, stream>>>(q, k, v, wq, wk, conv_w,
                                       qt, kt, vq, wqb3, wkb3, wt3);
  fused_qk_gemm<<<576, 256, 0, stream>>>(qt, kt, wt3, wqb3, wkb3,
                                         nq_w, nk_w, bq, bk, qp, kq);
  attn_flash<<<1152, 256, 0, stream>>>(qp, kq, vq, out);
}

// Round 4
// 148.610 us; speedup vs baseline: 1.5921x; 1.0242x over previous
//
#include <hip/hip_runtime.h>
#include <hip/hip_bf16.h>

namespace {
constexpr int kB = 8;
constexpr int kC = 64;
constexpr int kH = 48;
constexpr int kW = 48;
constexpr int kS = kH * kW;          // 2304
constexpr float kEps = 1.1920929e-07f;
// 0.25 (1/sqrt(head_dim)) * log2(e): lets attention use raw v_exp_f32 (2^x)
constexpr float kQScale = 0.25f * 1.4426950408889634f;
}

typedef __attribute__((ext_vector_type(8))) short short8;   // 8 bf16 (4 VGPR)
typedef __attribute__((ext_vector_type(4))) float f32x4;

// fp32 -> bf16 (round-nearest-even), bit-level
__device__ __forceinline__ short f2bf(float x) {
  unsigned u = __float_as_uint(x);
  u += 0x7fffu + ((u >> 16) & 1u);
  return (short)(u >> 16);
}
__device__ __forceinline__ float bf2f(short s) {
  return __uint_as_float(((unsigned)(unsigned short)s) << 16);
}
__device__ __forceinline__ float fexp2(float x) {
  return __builtin_amdgcn_exp2f(x);   // v_exp_f32 (2^x)
}

// ---------------------------------------------------------------------------
// F1: fused prep (unchanged from round 3).
// ---------------------------------------------------------------------------
__global__ __launch_bounds__(256) void fused_prep(
    const float* __restrict__ q, const float* __restrict__ k,
    const float* __restrict__ v, const float* __restrict__ wq,
    const float* __restrict__ wk, const float* __restrict__ conv_w,
    short* __restrict__ qt, short* __restrict__ kt, short* __restrict__ vq,
    short* __restrict__ wqb3, short* __restrict__ wkb3, short* __restrict__ wt3) {
  const int blk = blockIdx.x;
  if (blk < 576) {
    __shared__ float tile[64][65];
    const int zz = blk / 36;         // b*2 + which
    const int bx = blk % 36;
    const int b = zz >> 1;
    const float* src = (zz & 1) ? k : q;
    short* dst = (zz & 1) ? kt : qt;
    const int s0 = bx * 64;
    const int tx = threadIdx.x & 63;
    const int ty = threadIdx.x >> 6;
#pragma unroll
    for (int r = 0; r < 16; ++r) {
      int c = r * 4 + ty;
      tile[c][tx] = src[((size_t)b * kC + c) * kS + s0 + tx];
    }
    __syncthreads();
#pragma unroll
    for (int r = 0; r < 16; ++r) {
      int s = r * 4 + ty;
      dst[((size_t)b * kS + s0 + s) * kC + tx] = f2bf(tile[tx][s]);
    }
  } else if (blk < 1152) {
    // v -> fragment-major vq. One short8 per thread, coalesced store.
    int g = (blk - 576) * 256 + threadIdx.x;   // short8 index, < 147456
    int bb = g / 18432;                        // 72*4*64 short8 per batch
    int rem = g - bb * 18432;
    int jseg = rem >> 8;                       // 0..71
    int sub = rem & 255;
    int d = sub >> 6;                          // 0..3
    int Lq = sub & 63;                         // layout lane slot
    const float* src = v + ((size_t)(bb * 64 + d * 16 + (Lq & 15))) * kS
                         + jseg * 32 + (Lq >> 4) * 8;
    float4 x0 = *reinterpret_cast<const float4*>(src);
    float4 x1 = *reinterpret_cast<const float4*>(src + 4);
    short8 o;
    o[0] = f2bf(x0.x); o[1] = f2bf(x0.y); o[2] = f2bf(x0.z); o[3] = f2bf(x0.w);
    o[4] = f2bf(x1.x); o[5] = f2bf(x1.y); o[6] = f2bf(x1.z); o[7] = f2bf(x1.w);
    *reinterpret_cast<short8*>(vq + (size_t)g * 8) = o;
  } else {
    int idx = (blk - 1152) * 256 + threadIdx.x;
    if (idx < 4096) {
      int j = idx & 7, Lw = (idx >> 3) & 63, slab = idx >> 9;
      int nt = slab & 3, kh = slab >> 2;
      int e = nt * 16 + (Lw & 15), c = kh * 32 + (Lw >> 4) * 8 + j;
      wqb3[idx] = f2bf(wq[e * 64 + c]);
    } else if (idx < 8192) {
      int i2 = idx - 4096;
      int j = i2 & 7, Lw = (i2 >> 3) & 63, slab = i2 >> 9;
      int nt = slab & 3, kh = slab >> 2;
      int e = nt * 16 + (Lw & 15), c = kh * 32 + (Lw >> 4) * 8 + j;
      wkb3[i2] = f2bf(wk[e * 64 + c]);
    } else {
      int i3 = idx - 8192;   // < 36864
      int j = i3 & 7, Lw = (i3 >> 3) & 63, slab = i3 >> 9;   // 0..71
      int nt = slab & 3, kh = (slab >> 2) & 1, tap = slab >> 3;
      int co = nt * 16 + (Lw & 15), ci = kh * 32 + (Lw >> 4) * 8 + j;
      wt3[i3] = f2bf(conv_w[co * 576 + ci * 9 + tap]);
    }
  }
}

// ---------------------------------------------------------------------------
// F2: fused q/k projection GEMMs (unchanged from round 3).
// ---------------------------------------------------------------------------
__global__ __launch_bounds__(256) void fused_qk_gemm(
    const short* __restrict__ qt, const short* __restrict__ kt,
    const short* __restrict__ wt3, const short* __restrict__ wqb3,
    const short* __restrict__ wkb3,
    const float* __restrict__ nq_w, const float* __restrict__ nk_w,
    const float* __restrict__ bq, const float* __restrict__ bk,
    short* __restrict__ qp, short* __restrict__ kq) {
  __shared__ __align__(16) short Qs[164][72];   // q: halo tile / k: 64-row tile
  __shared__ __align__(16) short ln[4][16][80];
  const int blk = blockIdx.x;
  const int t = threadIdx.x;
  const int ws = t >> 6;
  const int L = t & 63;
  const int quad = L >> 4;
  const int l16 = L & 15;
  const short8 zero8 = {0, 0, 0, 0, 0, 0, 0, 0};

  if (blk < 288) {
    // ---- q path ----
    const int b = blk / 36;
    const int S0 = (blk % 36) * 64;
    const int sBase = S0 + ws * 16;
    const int s = sBase + l16;
    const int h = s / kW, w = s % kW;

    const short* qtb = qt + (size_t)b * kS * kC;
#pragma unroll
    for (int it = 0; it < 6; ++it) {
      int idx = it * 256 + t;
      if (idx < 164 * 8) {
        int r = idx >> 3, sg = idx & 7;
        int srow = S0 - 49 + r;
        srow = srow < 0 ? 0 : (srow >= kS ? kS - 1 : srow);
        *reinterpret_cast<int4*>(&Qs[r][sg * 8]) =
            *reinterpret_cast<const int4*>(qtb + (size_t)srow * kC + sg * 8);
      }
    }
    __syncthreads();

    const int baseLocal = ws * 16 + l16 + 49;
    f32x4 acc[4] = {{0.f, 0.f, 0.f, 0.f}, {0.f, 0.f, 0.f, 0.f},
                    {0.f, 0.f, 0.f, 0.f}, {0.f, 0.f, 0.f, 0.f}};
#pragma unroll
    for (int tap = 0; tap < 9; ++tap) {
      const int dh = tap / 3 - 1, dw = tap % 3 - 1;
      const bool valid = (unsigned)(h + dh) < (unsigned)kH &&
                         (unsigned)(w + dw) < (unsigned)kW;
      const int local = baseLocal + dh * kW + dw;
#pragma unroll
      for (int kh = 0; kh < 2; ++kh) {
        short8 af = *reinterpret_cast<const short8*>(&Qs[local][kh * 32 + quad * 8]);
        af = valid ? af : zero8;
        const short* wb = wt3 + ((tap * 2 + kh) * 4) * 512 + L * 8;
#pragma unroll
        for (int nt = 0; nt < 4; ++nt) {
          short8 bf = *reinterpret_cast<const short8*>(wb + nt * 512);  // coalesced
          acc[nt] = __builtin_amdgcn_mfma_f32_16x16x32_bf16(af, bf, acc[nt], 0, 0, 0);
        }
      }
    }
    float rstd[4];
#pragma unroll
    for (int reg = 0; reg < 4; ++reg) {
      float pr = acc[0][reg] * acc[0][reg] + acc[1][reg] * acc[1][reg]
               + acc[2][reg] * acc[2][reg] + acc[3][reg] * acc[3][reg];
      pr += __shfl_xor(pr, 1, 64);
      pr += __shfl_xor(pr, 2, 64);
      pr += __shfl_xor(pr, 4, 64);
      pr += __shfl_xor(pr, 8, 64);
      rstd[reg] = rsqrtf(pr * (1.0f / kC) + kEps);
    }
#pragma unroll
    for (int nt = 0; nt < 4; ++nt) {
      float g = nq_w[nt * 16 + l16];
#pragma unroll
      for (int reg = 0; reg < 4; ++reg) {
        ln[ws][quad * 4 + reg][nt * 16 + l16] = f2bf(acc[nt][reg] * rstd[reg] * g);
      }
    }
    __syncthreads();
    f32x4 acc2[4] = {{0.f, 0.f, 0.f, 0.f}, {0.f, 0.f, 0.f, 0.f},
                     {0.f, 0.f, 0.f, 0.f}, {0.f, 0.f, 0.f, 0.f}};
#pragma unroll
    for (int kh = 0; kh < 2; ++kh) {
      short8 af = *reinterpret_cast<const short8*>(&ln[ws][l16][kh * 32 + quad * 8]);
      const short* wb = wqb3 + (kh * 4) * 512 + L * 8;
#pragma unroll
      for (int nt = 0; nt < 4; ++nt) {
        short8 bf = *reinterpret_cast<const short8*>(wb + nt * 512);   // coalesced
        acc2[nt] = __builtin_amdgcn_mfma_f32_16x16x32_bf16(af, bf, acc2[nt], 0, 0, 0);
      }
    }
#pragma unroll
    for (int nt = 0; nt < 4; ++nt) {
      const int e = nt * 16 + l16;
      float bias = bq[e];
#pragma unroll
      for (int reg = 0; reg < 4; ++reg) {
        qp[((size_t)b * kS + sBase + quad * 4 + reg) * kC + e] =
            f2bf((acc2[nt][reg] + bias) * kQScale);
      }
    }
  } else {
    // ---- k path ----
    const int idx = blk - 288;
    const int b = idx / 36;
    const int S0 = (idx % 36) * 64;
    const int sBase = S0 + ws * 16;

    const short* ktb = kt + ((size_t)b * kS + S0) * kC;
#pragma unroll
    for (int it = 0; it < 2; ++it) {
      int r = it * 32 + (t >> 3), sg = t & 7;
      *reinterpret_cast<int4*>(&Qs[r][sg * 8]) =
          *reinterpret_cast<const int4*>(ktb + (size_t)r * kC + sg * 8);
    }
    __syncthreads();

    short8 af0 = *reinterpret_cast<const short8*>(&Qs[ws * 16 + l16][quad * 8]);
    short8 af1 = *reinterpret_cast<const short8*>(&Qs[ws * 16 + l16][32 + quad * 8]);

    float xs[16];
#pragma unroll
    for (int j = 0; j < 8; ++j) { xs[j] = bf2f(af0[j]); xs[8 + j] = bf2f(af1[j]); }
    float sum = 0.f;
#pragma unroll
    for (int j = 0; j < 16; ++j) sum = fmaf(xs[j], xs[j], sum);
    sum += __shfl_xor(sum, 16, 64);
    sum += __shfl_xor(sum, 32, 64);
    float rstd = rsqrtf(sum * (1.0f / kC) + kEps);

    const float* n0 = nk_w + quad * 8;
#pragma unroll
    for (int j = 0; j < 8; ++j) {
      af0[j] = f2bf(xs[j] * rstd * n0[j]);
      af1[j] = f2bf(xs[8 + j] * rstd * n0[32 + j]);
    }

    f32x4 acc[4] = {{0.f, 0.f, 0.f, 0.f}, {0.f, 0.f, 0.f, 0.f},
                    {0.f, 0.f, 0.f, 0.f}, {0.f, 0.f, 0.f, 0.f}};
#pragma unroll
    for (int nt = 0; nt < 4; ++nt) {
      short8 bf0 = *reinterpret_cast<const short8*>(
          wkb3 + (0 * 4 + nt) * 512 + L * 8);
      short8 bf1 = *reinterpret_cast<const short8*>(
          wkb3 + (1 * 4 + nt) * 512 + L * 8);
      acc[nt] = __builtin_amdgcn_mfma_f32_16x16x32_bf16(af0, bf0, acc[nt], 0, 0, 0);
      acc[nt] = __builtin_amdgcn_mfma_f32_16x16x32_bf16(af1, bf1, acc[nt], 0, 0, 0);
    }
    // fragment-major store (see header comment)
    short* kqb = kq + (size_t)b * 147456;   // 72 * 2048 shorts per batch
#pragma unroll
    for (int nt = 0; nt < 4; ++nt) {
      const int e = nt * 16 + l16;
      const int hp = nt >> 1;
      const int quadp = ((nt & 1) << 1) | (l16 >> 3);
      const int elem = l16 & 7;
      float bias = bk[e];
#pragma unroll
      for (int reg = 0; reg < 4; ++reg) {
        int s = sBase + quad * 4 + reg;
        int jseg = s >> 5, jrow = s & 31;
        int c = (jrow >> 2) & 1;
        int l16p = ((jrow >> 3) << 2) | (jrow & 3);
        kqb[((((size_t)jseg * 2 + hp) * 2 + c) * 64 + quadp * 16 + l16p) * 8 + elem] =
            f2bf(acc[nt][reg] + bias);
      }
    }
  }
}

// ---------------------------------------------------------------------------
// K3: flash attention, register-direct fragment-major (round-3 structure) +
// (a) softmax denominator on the MFMA pipe: one extra MFMA per hl against a
//     constant ones-row A-frag accumulates l into Ul[hl] (quad0/reg0 lanes);
//     kills 14 fp32 adds/jt on the binding VALU pipe + epilogue shuffles.
// (b) 2-deep register prefetch (two named buffers, branchless peeled loop):
//     loads issued ~1.5 phases before use (~350+ cyc cover vs ~250 cyc L2).
// grid 1152: b=blk&7 (XCD-aligned), hp=(blk>>3)&1, i0=(blk>>4)*32.
// ---------------------------------------------------------------------------
#define LOADT(K0, K1, V0, V1, V2, V3, JT)                                      \
  do {                                                                         \
    const short* kb_ = kbase + (size_t)(JT) * 4096;                            \
    const short* vb_ = vbase + (size_t)(JT) * 4096;                            \
    K0 = *reinterpret_cast<const short8*>(kb_);                                \
    K1 = *reinterpret_cast<const short8*>(kb_ + 512);                          \
    V0 = *reinterpret_cast<const short8*>(vb_);                                \
    V1 = *reinterpret_cast<const short8*>(vb_ + 512);                          \
    V2 = *reinterpret_cast<const short8*>(vb_ + 1024);                         \
    V3 = *reinterpret_cast<const short8*>(vb_ + 1536);                         \
  } while (0)

#define PHASE(K0, K1, V0, V1, V2, V3)                                          \
  do {                                                                         \
    _Pragma("unroll")                                                          \
    for (int hl = 0; hl < 2; ++hl) {                                           \
      f32x4 s0 = __builtin_amdgcn_mfma_f32_16x16x32_bf16(K0, qm[hl], zc, 0, 0, 0); \
      f32x4 s1 = __builtin_amdgcn_mfma_f32_16x16x32_bf16(K1, qm[hl], zc, 0, 0, 0); \
      float e0 = fexp2(s0[0]), e1 = fexp2(s0[1]);                              \
      float e2 = fexp2(s0[2]), e3 = fexp2(s0[3]);                              \
      float f0 = fexp2(s1[0]), f1 = fexp2(s1[1]);                              \
      float f2 = fexp2(s1[2]), f3 = fexp2(s1[3]);                              \
      union { __hip_bfloat162 h2[4]; short8 s8; } cv;                          \
      cv.h2[0] = __float22bfloat162_rn(make_float2(e0, e1));                   \
      cv.h2[1] = __float22bfloat162_rn(make_float2(e2, e3));                   \
      cv.h2[2] = __float22bfloat162_rn(make_float2(f0, f1));                   \
      cv.h2[3] = __float22bfloat162_rn(make_float2(f2, f3));                   \
      U[hl][0] = __builtin_amdgcn_mfma_f32_16x16x32_bf16(V0, cv.s8, U[hl][0], 0, 0, 0); \
      U[hl][1] = __builtin_amdgcn_mfma_f32_16x16x32_bf16(V1, cv.s8, U[hl][1], 0, 0, 0); \
      U[hl][2] = __builtin_amdgcn_mfma_f32_16x16x32_bf16(V2, cv.s8, U[hl][2], 0, 0, 0); \
      U[hl][3] = __builtin_amdgcn_mfma_f32_16x16x32_bf16(V3, cv.s8, U[hl][3], 0, 0, 0); \
      Ul[hl]   = __builtin_amdgcn_mfma_f32_16x16x32_bf16(af_l, cv.s8, Ul[hl], 0, 0, 0); \
    }                                                                          \
  } while (0)

__global__ __launch_bounds__(256, 4) void attn_flash(
    const short* __restrict__ qp, const short* __restrict__ kq,
    const short* __restrict__ vq, float* __restrict__ out) {
  __shared__ float pl[4][16][2];            // [ws][i16][hl]
  __shared__ float Li[32][2];               // 0.25 / l
  __shared__ __align__(16) float slab[16][66];

  const int blk = blockIdx.x;
  const int b = blk & 7;           // low bits -> all of batch b on one XCD (L2 fit)
  const int idx = blk >> 3;        // 0..143
  const int hp = idx & 1;          // head pair: heads 2hp, 2hp+1
  const int i0 = (idx >> 1) * 32;
  const int t = threadIdx.x;
  const int ws = t >> 6;
  const int isub = ws & 1;
  const int jhalf = ws >> 1;
  const int L = t & 63;
  const int quad = L >> 4;
  const int l16 = L & 15;

  const f32x4 zc = {0.f, 0.f, 0.f, 0.f};
  const short8 z8 = {0, 0, 0, 0, 0, 0, 0, 0};
  const short ob = (short)0x3F80;   // bf16 1.0
  const short8 ones8 = {ob, ob, ob, ob, ob, ob, ob, ob};
  // ones-row A-frag: A[0][k]=1, A[r>0][k]=0 -> lanes with l16==0 hold ones.
  const short8 af_l = (l16 == 0) ? ones8 : z8;

  // Q window (B operand, K=32 = this head pair's d window)
  const short* qrow = qp + ((size_t)b * kS + i0 + isub * 16 + l16) * kC + hp * 32;
  const short8 qw = *reinterpret_cast<const short8*>(qrow + quad * 8);
  const bool lo = quad < 2;
  const short8 qm[2] = {lo ? qw : z8, lo ? z8 : qw};   // local heads 0,1 of the pair

  // Fragment-major bases: every load below is base + (lane)*16B, coalesced.
  const short* kbase =
      kq + (((size_t)(b * 72 + jhalf) * 2 + hp) * 2 * 64 + L) * 8;
  const short* vbase = vq + ((size_t)(b * 72 + jhalf) * 4 * 64 + L) * 8;

  f32x4 U[2][4];   // [hl][dtile]: lane holds d=dtile*16+quad*4+reg, i=l16
#pragma unroll
  for (int hl = 0; hl < 2; ++hl)
#pragma unroll
    for (int d = 0; d < 4; ++d) U[hl][d] = zc;
  f32x4 Ul[2] = {zc, zc};   // denominator: quad0/reg0 lane l16 holds l_i

  // 2-deep prefetch: tiles jt and jt+1 in named register buffers.
  short8 ka0, ka1, va0, va1, va2, va3;
  short8 kb0, kb1, vb0, vb1, vb2, vb3;
  LOADT(ka0, ka1, va0, va1, va2, va3, 0);
  LOADT(kb0, kb1, vb0, vb1, vb2, vb3, 1);

  for (int jt = 0; jt < 34; jt += 2) {
    PHASE(ka0, ka1, va0, va1, va2, va3);
    LOADT(ka0, ka1, va0, va1, va2, va3, jt + 2);
    PHASE(kb0, kb1, vb0, vb1, vb2, vb3);
    LOADT(kb0, kb1, vb0, vb1, vb2, vb3, jt + 3);
  }
  PHASE(ka0, ka1, va0, va1, va2, va3);   // jt = 34
  PHASE(kb0, kb1, vb0, vb1, vb2, vb3);   // jt = 35

  // ---- epilogue (first barrier re-syncs the free-running waves) ----
  if (quad == 0) {
#pragma unroll
    for (int hl = 0; hl < 2; ++hl) pl[ws][l16][hl] = Ul[hl][0];
  }
  __syncthreads();
  if (t < 64) {
    const int i = t >> 1, h2 = t & 1;    // i 0..31 (local sub-row)
    Li[i][h2] = 0.25f / (pl[i >> 4][i & 15][h2] + pl[(i >> 4) + 2][i & 15][h2]);
  }
  __syncthreads();
  float c2[2];
#pragma unroll
  for (int hl = 0; hl < 2; ++hl) c2[hl] = Li[isub * 16 + l16][hl];

  // jhalf-pair reduce, one d-tile per phase
#pragma unroll
  for (int d = 0; d < 4; ++d) {
    if (jhalf == 1) {
#pragma unroll
      for (int hl = 0; hl < 2; ++hl)
#pragma unroll
        for (int reg = 0; reg < 4; ++reg)
          slab[(isub * 2 + hl) * 4 + reg][L] = U[hl][d][reg];
    }
    __syncthreads();
    if (jhalf == 0) {
      float of[4] = {0.f, 0.f, 0.f, 0.f};
#pragma unroll
      for (int hl = 0; hl < 2; ++hl) {
#pragma unroll
        for (int reg = 0; reg < 4; ++reg) {
          float tot = U[hl][d][reg] + slab[(isub * 2 + hl) * 4 + reg][L];
          of[reg] += tot * c2[hl];
        }
      }
      float* op = out + ((size_t)b * kS + i0 + isub * 16 + l16) * kC + d * 16 + quad * 4;
#pragma unroll
      for (int reg = 0; reg < 4; ++reg) atomicAdd(op + reg, of[reg]);
    }
    __syncthreads();
  }
}

// ---------------------------------------------------------------------------
extern "C" void kernel_launch(void* const* d_in, const int* in_sizes, int n_in,
                              void* d_out, int out_size, void* d_ws, size_t ws_size,
                              hipStream_t stream) {
  const float* q      = (const float*)d_in[0];
  const float* k      = (const float*)d_in[1];
  const float* v      = (const float*)d_in[2];
  const float* conv_w = (const float*)d_in[3];
  const float* nq_w   = (const float*)d_in[4];
  const float* nk_w   = (const float*)d_in[5];
  const float* wq     = (const float*)d_in[6];
  const float* bq     = (const float*)d_in[7];
  const float* wk     = (const float*)d_in[8];
  const float* bk     = (const float*)d_in[9];
  float* out = (float*)d_out;

  const size_t N = (size_t)kB * kS * kC;   // 1,179,648
  short* qt   = (short*)d_ws;     // bf16 [b][s][c]
  short* kt   = qt + N;
  short* vq   = kt + N;           // bf16 fragment-major V
  short* qp   = vq + N;           // bf16 [b][s][64], pre-scaled by 0.25*log2(e)
  short* kq   = qp + N;           // bf16 fragment-major K-proj
  short* wqb3 = kq + N;           // frag-major bf16
  short* wkb3 = wqb3 + 4096;
  short* wt3  = wkb3 + 4096;      // frag-major bf16 [72 slabs][512]

  // head-pair blocks combine via atomicAdd -> zero the output first (capturable)
  hipMemsetAsync(d_out, 0, out_size, stream);

  fused_prep<<<1328, 256, 0, stream>>>(q, k, v, wq, wk, conv_w,
                                       qt, kt, vq, wqb3, wkb3, wt3);
  fused_qk_gemm<<<576, 256, 0, stream>>>(qt, kt, wt3, wqb3, wkb3,
                                         nq_w, nk_w, bq, bk, qp, kq);
  attn_flash<<<1152, 256, 0, stream>>>(qp, kq, vq, out);
}

// Round 6
// 144.003 us; speedup vs baseline: 1.6431x; 1.0320x over previous
//
#include <hip/hip_runtime.h>
#include <hip/hip_bf16.h>

namespace {
constexpr int kB = 8;
constexpr int kC = 64;
constexpr int kH = 48;
constexpr int kW = 48;
constexpr int kS = kH * kW;          // 2304
constexpr float kEps = 1.1920929e-07f;
// 0.25 (1/sqrt(head_dim)) * log2(e): lets attention use raw v_exp_f32 (2^x)
constexpr float kQScale = 0.25f * 1.4426950408889634f;
}

typedef __attribute__((ext_vector_type(8))) short short8;   // 8 bf16 (4 VGPR)
typedef __attribute__((ext_vector_type(4))) float f32x4;

// fp32 -> bf16 (round-nearest-even), bit-level
__device__ __forceinline__ short f2bf(float x) {
  unsigned u = __float_as_uint(x);
  u += 0x7fffu + ((u >> 16) & 1u);
  return (short)(u >> 16);
}
__device__ __forceinline__ float bf2f(short s) {
  return __uint_as_float(((unsigned)(unsigned short)s) << 16);
}
__device__ __forceinline__ float fexp2(float x) {
  return __builtin_amdgcn_exp2f(x);   // v_exp_f32 (2^x)
}

// ---------------------------------------------------------------------------
// D1: prep_lite -- v fragment-major + weight repack + zero(out).
// (q/k transposes moved into the gemm kernel; memset dispatch absorbed here.)
// grid 1328: [0,576) v | [576,752) weights | [752,1328) zero out.
// ---------------------------------------------------------------------------
__global__ __launch_bounds__(256) void prep_lite(
    const float* __restrict__ v, const float* __restrict__ wq,
    const float* __restrict__ wk, const float* __restrict__ conv_w,
    short* __restrict__ vq, short* __restrict__ wqb3, short* __restrict__ wkb3,
    short* __restrict__ wt3, float* __restrict__ out) {
  const int blk = blockIdx.x;
  const int t = threadIdx.x;
  if (blk < 576) {
    // v -> fragment-major vq. One short8 per thread, coalesced store.
    int g = blk * 256 + t;                     // short8 index, < 147456
    int bb = g / 18432;                        // 72*4*64 short8 per batch
    int rem = g - bb * 18432;
    int jseg = rem >> 8;                       // 0..71
    int sub = rem & 255;
    int d = sub >> 6;                          // 0..3
    int Lq = sub & 63;                         // layout lane slot
    const float* src = v + ((size_t)(bb * 64 + d * 16 + (Lq & 15))) * kS
                         + jseg * 32 + (Lq >> 4) * 8;
    float4 x0 = *reinterpret_cast<const float4*>(src);
    float4 x1 = *reinterpret_cast<const float4*>(src + 4);
    short8 o;
    o[0] = f2bf(x0.x); o[1] = f2bf(x0.y); o[2] = f2bf(x0.z); o[3] = f2bf(x0.w);
    o[4] = f2bf(x1.x); o[5] = f2bf(x1.y); o[6] = f2bf(x1.z); o[7] = f2bf(x1.w);
    *reinterpret_cast<short8*>(vq + (size_t)g * 8) = o;
  } else if (blk < 752) {
    int idx = (blk - 576) * 256 + t;           // < 45056
    if (idx < 4096) {
      int j = idx & 7, Lw = (idx >> 3) & 63, slab = idx >> 9;
      int nt = slab & 3, kh = slab >> 2;
      int e = nt * 16 + (Lw & 15), c = kh * 32 + (Lw >> 4) * 8 + j;
      wqb3[idx] = f2bf(wq[e * 64 + c]);
    } else if (idx < 8192) {
      int i2 = idx - 4096;
      int j = i2 & 7, Lw = (i2 >> 3) & 63, slab = i2 >> 9;
      int nt = slab & 3, kh = slab >> 2;
      int e = nt * 16 + (Lw & 15), c = kh * 32 + (Lw >> 4) * 8 + j;
      wkb3[i2] = f2bf(wk[e * 64 + c]);
    } else {
      int i3 = idx - 8192;   // < 36864
      int j = i3 & 7, Lw = (i3 >> 3) & 63, slab = i3 >> 9;   // 0..71
      int nt = slab & 3, kh = (slab >> 2) & 1, tap = slab >> 3;
      int co = nt * 16 + (Lw & 15), ci = kh * 32 + (Lw >> 4) * 8 + j;
      wt3[i3] = f2bf(conv_w[co * 576 + ci * 9 + tap]);
    }
  } else {
    // zero the output (replaces hipMemsetAsync); 8 floats/thread, exact cover
    size_t i = (size_t)(blk - 752) * 256 + t;
    float4 z = make_float4(0.f, 0.f, 0.f, 0.f);
    *reinterpret_cast<float4*>(out + i * 8) = z;
    *reinterpret_cast<float4*>(out + i * 8 + 4) = z;
  }
}

// ---------------------------------------------------------------------------
// D2: q/k projection GEMMs, now self-staging from the ORIGINAL fp32 NCHW
// q/k tensors (transpose via fp32 LDS tile, bf16 convert in place) -- the
// separate transpose pass and the qt/kt workspace round-trip are gone.
// Qs fragment contents are bit-identical to previous rounds (same clamp).
// LDS: Qs 23.6K + ln 10.2K + tile 16.6K = 50.5 KB.
// ---------------------------------------------------------------------------
__global__ __launch_bounds__(256) void qk_gemm_t(
    const float* __restrict__ q, const float* __restrict__ k,
    const short* __restrict__ wt3, const short* __restrict__ wqb3,
    const short* __restrict__ wkb3,
    const float* __restrict__ nq_w, const float* __restrict__ nk_w,
    const float* __restrict__ bq, const float* __restrict__ bk,
    short* __restrict__ qp, short* __restrict__ kq) {
  __shared__ __align__(16) short Qs[164][72];   // q: halo tile / k: 64-row tile
  __shared__ __align__(16) short ln[4][16][80];
  __shared__ float tile[64][65];                // fp32 transpose staging
  const int blk = blockIdx.x;
  const int t = threadIdx.x;
  const int ws = t >> 6;
  const int L = t & 63;
  const int quad = L >> 4;
  const int l16 = L & 15;
  const int tx = t & 63;
  const int ty = t >> 6;
  const short8 zero8 = {0, 0, 0, 0, 0, 0, 0, 0};

  if (blk < 288) {
    // ---- q path ----
    const int b = blk / 36;
    const int S0 = (blk % 36) * 64;
    const int sBase = S0 + ws * 16;
    const int s = sBase + l16;
    const int h = s / kW, w = s % kW;

    // stage halo rows S0-49 .. S0+114 (clamped) in 3 passes of 64
    const float* qb = q + (size_t)b * kC * kS;
#pragma unroll
    for (int p = 0; p < 3; ++p) {
      int scol = S0 - 49 + p * 64 + tx;
      scol = scol < 0 ? 0 : (scol >= kS ? kS - 1 : scol);
#pragma unroll
      for (int r = 0; r < 16; ++r) {
        int c = r * 4 + ty;
        tile[c][tx] = qb[(size_t)c * kS + scol];
      }
      __syncthreads();
#pragma unroll
      for (int r = 0; r < 16; ++r) {
        int j = r * 4 + ty;
        int srow = p * 64 + j;
        if (srow < 164) Qs[srow][tx] = f2bf(tile[tx][j]);
      }
      __syncthreads();
    }

    const int baseLocal = ws * 16 + l16 + 49;
    f32x4 acc[4] = {{0.f, 0.f, 0.f, 0.f}, {0.f, 0.f, 0.f, 0.f},
                    {0.f, 0.f, 0.f, 0.f}, {0.f, 0.f, 0.f, 0.f}};
#pragma unroll
    for (int tap = 0; tap < 9; ++tap) {
      const int dh = tap / 3 - 1, dw = tap % 3 - 1;
      const bool valid = (unsigned)(h + dh) < (unsigned)kH &&
                         (unsigned)(w + dw) < (unsigned)kW;
      const int local = baseLocal + dh * kW + dw;
#pragma unroll
      for (int kh = 0; kh < 2; ++kh) {
        short8 af = *reinterpret_cast<const short8*>(&Qs[local][kh * 32 + quad * 8]);
        af = valid ? af : zero8;
        const short* wb = wt3 + ((tap * 2 + kh) * 4) * 512 + L * 8;
#pragma unroll
        for (int nt = 0; nt < 4; ++nt) {
          short8 bf = *reinterpret_cast<const short8*>(wb + nt * 512);  // coalesced
          acc[nt] = __builtin_amdgcn_mfma_f32_16x16x32_bf16(af, bf, acc[nt], 0, 0, 0);
        }
      }
    }
    float rstd[4];
#pragma unroll
    for (int reg = 0; reg < 4; ++reg) {
      float pr = acc[0][reg] * acc[0][reg] + acc[1][reg] * acc[1][reg]
               + acc[2][reg] * acc[2][reg] + acc[3][reg] * acc[3][reg];
      pr += __shfl_xor(pr, 1, 64);
      pr += __shfl_xor(pr, 2, 64);
      pr += __shfl_xor(pr, 4, 64);
      pr += __shfl_xor(pr, 8, 64);
      rstd[reg] = rsqrtf(pr * (1.0f / kC) + kEps);
    }
#pragma unroll
    for (int nt = 0; nt < 4; ++nt) {
      float g = nq_w[nt * 16 + l16];
#pragma unroll
      for (int reg = 0; reg < 4; ++reg) {
        ln[ws][quad * 4 + reg][nt * 16 + l16] = f2bf(acc[nt][reg] * rstd[reg] * g);
      }
    }
    __syncthreads();
    f32x4 acc2[4] = {{0.f, 0.f, 0.f, 0.f}, {0.f, 0.f, 0.f, 0.f},
                     {0.f, 0.f, 0.f, 0.f}, {0.f, 0.f, 0.f, 0.f}};
#pragma unroll
    for (int kh = 0; kh < 2; ++kh) {
      short8 af = *reinterpret_cast<const short8*>(&ln[ws][l16][kh * 32 + quad * 8]);
      const short* wb = wqb3 + (kh * 4) * 512 + L * 8;
#pragma unroll
      for (int nt = 0; nt < 4; ++nt) {
        short8 bf = *reinterpret_cast<const short8*>(wb + nt * 512);   // coalesced
        acc2[nt] = __builtin_amdgcn_mfma_f32_16x16x32_bf16(af, bf, acc2[nt], 0, 0, 0);
      }
    }
#pragma unroll
    for (int nt = 0; nt < 4; ++nt) {
      const int e = nt * 16 + l16;
      float bias = bq[e];
#pragma unroll
      for (int reg = 0; reg < 4; ++reg) {
        qp[((size_t)b * kS + sBase + quad * 4 + reg) * kC + e] =
            f2bf((acc2[nt][reg] + bias) * kQScale);
      }
    }
  } else {
    // ---- k path ----
    const int idx = blk - 288;
    const int b = idx / 36;
    const int S0 = (idx % 36) * 64;
    const int sBase = S0 + ws * 16;

    // stage 64 rows S0..S0+63 (single pass)
    const float* kb = k + (size_t)b * kC * kS;
#pragma unroll
    for (int r = 0; r < 16; ++r) {
      int c = r * 4 + ty;
      tile[c][tx] = kb[(size_t)c * kS + S0 + tx];
    }
    __syncthreads();
#pragma unroll
    for (int r = 0; r < 16; ++r) {
      int j = r * 4 + ty;
      Qs[j][tx] = f2bf(tile[tx][j]);
    }
    __syncthreads();

    short8 af0 = *reinterpret_cast<const short8*>(&Qs[ws * 16 + l16][quad * 8]);
    short8 af1 = *reinterpret_cast<const short8*>(&Qs[ws * 16 + l16][32 + quad * 8]);

    float xs[16];
#pragma unroll
    for (int j = 0; j < 8; ++j) { xs[j] = bf2f(af0[j]); xs[8 + j] = bf2f(af1[j]); }
    float sum = 0.f;
#pragma unroll
    for (int j = 0; j < 16; ++j) sum = fmaf(xs[j], xs[j], sum);
    sum += __shfl_xor(sum, 16, 64);
    sum += __shfl_xor(sum, 32, 64);
    float rstd = rsqrtf(sum * (1.0f / kC) + kEps);

    const float* n0 = nk_w + quad * 8;
#pragma unroll
    for (int j = 0; j < 8; ++j) {
      af0[j] = f2bf(xs[j] * rstd * n0[j]);
      af1[j] = f2bf(xs[8 + j] * rstd * n0[32 + j]);
    }

    f32x4 acc[4] = {{0.f, 0.f, 0.f, 0.f}, {0.f, 0.f, 0.f, 0.f},
                    {0.f, 0.f, 0.f, 0.f}, {0.f, 0.f, 0.f, 0.f}};
#pragma unroll
    for (int nt = 0; nt < 4; ++nt) {
      short8 bf0 = *reinterpret_cast<const short8*>(
          wkb3 + (0 * 4 + nt) * 512 + L * 8);
      short8 bf1 = *reinterpret_cast<const short8*>(
          wkb3 + (1 * 4 + nt) * 512 + L * 8);
      acc[nt] = __builtin_amdgcn_mfma_f32_16x16x32_bf16(af0, bf0, acc[nt], 0, 0, 0);
      acc[nt] = __builtin_amdgcn_mfma_f32_16x16x32_bf16(af1, bf1, acc[nt], 0, 0, 0);
    }
    // fragment-major store
    short* kqb = kq + (size_t)b * 147456;   // 72 * 2048 shorts per batch
#pragma unroll
    for (int nt = 0; nt < 4; ++nt) {
      const int hp = nt >> 1;
      const int quadp = ((nt & 1) << 1) | (l16 >> 3);
      const int elem = l16 & 7;
      float bias = bk[nt * 16 + l16];
#pragma unroll
      for (int reg = 0; reg < 4; ++reg) {
        int s = sBase + quad * 4 + reg;
        int jseg = s >> 5, jrow = s & 31;
        int c = (jrow >> 2) & 1;
        int l16p = ((jrow >> 3) << 2) | (jrow & 3);
        kqb[((((size_t)jseg * 2 + hp) * 2 + c) * 64 + quadp * 16 + l16p) * 8 + elem] =
            f2bf(acc[nt][reg] + bias);
      }
    }
  }
}

// ---------------------------------------------------------------------------
// D3: flash attention (identical to round 4: register-direct fragment-major,
// ones-row-MFMA denominator, 2-deep register prefetch).
// ---------------------------------------------------------------------------
#define LOADT(K0, K1, V0, V1, V2, V3, JT)                                      \
  do {                                                                         \
    const short* kb_ = kbase + (size_t)(JT) * 4096;                            \
    const short* vb_ = vbase + (size_t)(JT) * 4096;                            \
    K0 = *reinterpret_cast<const short8*>(kb_);                                \
    K1 = *reinterpret_cast<const short8*>(kb_ + 512);                          \
    V0 = *reinterpret_cast<const short8*>(vb_);                                \
    V1 = *reinterpret_cast<const short8*>(vb_ + 512);                          \
    V2 = *reinterpret_cast<const short8*>(vb_ + 1024);                         \
    V3 = *reinterpret_cast<const short8*>(vb_ + 1536);                         \
  } while (0)

#define PHASE(K0, K1, V0, V1, V2, V3)                                          \
  do {                                                                         \
    _Pragma("unroll")                                                          \
    for (int hl = 0; hl < 2; ++hl) {                                           \
      f32x4 s0 = __builtin_amdgcn_mfma_f32_16x16x32_bf16(K0, qm[hl], zc, 0, 0, 0); \
      f32x4 s1 = __builtin_amdgcn_mfma_f32_16x16x32_bf16(K1, qm[hl], zc, 0, 0, 0); \
      float e0 = fexp2(s0[0]), e1 = fexp2(s0[1]);                              \
      float e2 = fexp2(s0[2]), e3 = fexp2(s0[3]);                              \
      float f0 = fexp2(s1[0]), f1 = fexp2(s1[1]);                              \
      float f2 = fexp2(s1[2]), f3 = fexp2(s1[3]);                              \
      union { __hip_bfloat162 h2[4]; short8 s8; } cv;                          \
      cv.h2[0] = __float22bfloat162_rn(make_float2(e0, e1));                   \
      cv.h2[1] = __float22bfloat162_rn(make_float2(e2, e3));                   \
      cv.h2[2] = __float22bfloat162_rn(make_float2(f0, f1));                   \
      cv.h2[3] = __float22bfloat162_rn(make_float2(f2, f3));                   \
      U[hl][0] = __builtin_amdgcn_mfma_f32_16x16x32_bf16(V0, cv.s8, U[hl][0], 0, 0, 0); \
      U[hl][1] = __builtin_amdgcn_mfma_f32_16x16x32_bf16(V1, cv.s8, U[hl][1], 0, 0, 0); \
      U[hl][2] = __builtin_amdgcn_mfma_f32_16x16x32_bf16(V2, cv.s8, U[hl][2], 0, 0, 0); \
      U[hl][3] = __builtin_amdgcn_mfma_f32_16x16x32_bf16(V3, cv.s8, U[hl][3], 0, 0, 0); \
      Ul[hl]   = __builtin_amdgcn_mfma_f32_16x16x32_bf16(af_l, cv.s8, Ul[hl], 0, 0, 0); \
    }                                                                          \
  } while (0)

__global__ __launch_bounds__(256, 4) void attn_flash(
    const short* __restrict__ qp, const short* __restrict__ kq,
    const short* __restrict__ vq, float* __restrict__ out) {
  __shared__ float pl[4][16][2];            // [ws][i16][hl]
  __shared__ float Li[32][2];               // 0.25 / l
  __shared__ __align__(16) float slab[16][66];

  const int blk = blockIdx.x;
  const int b = blk & 7;           // low bits -> all of batch b on one XCD (L2 fit)
  const int idx = blk >> 3;        // 0..143
  const int hp = idx & 1;          // head pair: heads 2hp, 2hp+1
  const int i0 = (idx >> 1) * 32;
  const int t = threadIdx.x;
  const int ws = t >> 6;
  const int isub = ws & 1;
  const int jhalf = ws >> 1;
  const int L = t & 63;
  const int quad = L >> 4;
  const int l16 = L & 15;

  const f32x4 zc = {0.f, 0.f, 0.f, 0.f};
  const short8 z8 = {0, 0, 0, 0, 0, 0, 0, 0};
  const short ob = (short)0x3F80;   // bf16 1.0
  const short8 ones8 = {ob, ob, ob, ob, ob, ob, ob, ob};
  // ones-row A-frag: A[0][k]=1, A[r>0][k]=0 -> lanes with l16==0 hold ones.
  const short8 af_l = (l16 == 0) ? ones8 : z8;

  // Q window (B operand, K=32 = this head pair's d window)
  const short* qrow = qp + ((size_t)b * kS + i0 + isub * 16 + l16) * kC + hp * 32;
  const short8 qw = *reinterpret_cast<const short8*>(qrow + quad * 8);
  const bool lo = quad < 2;
  const short8 qm[2] = {lo ? qw : z8, lo ? z8 : qw};   // local heads 0,1 of the pair

  // Fragment-major bases: every load below is base + (lane)*16B, coalesced.
  const short* kbase =
      kq + (((size_t)(b * 72 + jhalf) * 2 + hp) * 2 * 64 + L) * 8;
  const short* vbase = vq + ((size_t)(b * 72 + jhalf) * 4 * 64 + L) * 8;

  f32x4 U[2][4];   // [hl][dtile]: lane holds d=dtile*16+quad*4+reg, i=l16
#pragma unroll
  for (int hl = 0; hl < 2; ++hl)
#pragma unroll
    for (int d = 0; d < 4; ++d) U[hl][d] = zc;
  f32x4 Ul[2] = {zc, zc};   // denominator: quad0/reg0 lane l16 holds l_i

  // 2-deep prefetch: tiles jt and jt+1 in named register buffers.
  short8 ka0, ka1, va0, va1, va2, va3;
  short8 kb0, kb1, vb0, vb1, vb2, vb3;
  LOADT(ka0, ka1, va0, va1, va2, va3, 0);
  LOADT(kb0, kb1, vb0, vb1, vb2, vb3, 1);

  for (int jt = 0; jt < 34; jt += 2) {
    PHASE(ka0, ka1, va0, va1, va2, va3);
    LOADT(ka0, ka1, va0, va1, va2, va3, jt + 2);
    PHASE(kb0, kb1, vb0, vb1, vb2, vb3);
    LOADT(kb0, kb1, vb0, vb1, vb2, vb3, jt + 3);
  }
  PHASE(ka0, ka1, va0, va1, va2, va3);   // jt = 34
  PHASE(kb0, kb1, vb0, vb1, vb2, vb3);   // jt = 35

  // ---- epilogue (first barrier re-syncs the free-running waves) ----
  if (quad == 0) {
#pragma unroll
    for (int hl = 0; hl < 2; ++hl) pl[ws][l16][hl] = Ul[hl][0];
  }
  __syncthreads();
  if (t < 64) {
    const int i = t >> 1, h2 = t & 1;    // i 0..31 (local sub-row)
    Li[i][h2] = 0.25f / (pl[i >> 4][i & 15][h2] + pl[(i >> 4) + 2][i & 15][h2]);
  }
  __syncthreads();
  float c2[2];
#pragma unroll
  for (int hl = 0; hl < 2; ++hl) c2[hl] = Li[isub * 16 + l16][hl];

  // jhalf-pair reduce, one d-tile per phase
#pragma unroll
  for (int d = 0; d < 4; ++d) {
    if (jhalf == 1) {
#pragma unroll
      for (int hl = 0; hl < 2; ++hl)
#pragma unroll
        for (int reg = 0; reg < 4; ++reg)
          slab[(isub * 2 + hl) * 4 + reg][L] = U[hl][d][reg];
    }
    __syncthreads();
    if (jhalf == 0) {
      float of[4] = {0.f, 0.f, 0.f, 0.f};
#pragma unroll
      for (int hl = 0; hl < 2; ++hl) {
#pragma unroll
        for (int reg = 0; reg < 4; ++reg) {
          float tot = U[hl][d][reg] + slab[(isub * 2 + hl) * 4 + reg][L];
          of[reg] += tot * c2[hl];
        }
      }
      float* op = out + ((size_t)b * kS + i0 + isub * 16 + l16) * kC + d * 16 + quad * 4;
#pragma unroll
      for (int reg = 0; reg < 4; ++reg) atomicAdd(op + reg, of[reg]);
    }
    __syncthreads();
  }
}

// ---------------------------------------------------------------------------
extern "C" void kernel_launch(void* const* d_in, const int* in_sizes, int n_in,
                              void* d_out, int out_size, void* d_ws, size_t ws_size,
                              hipStream_t stream) {
  const float* q      = (const float*)d_in[0];
  const float* k      = (const float*)d_in[1];
  const float* v      = (const float*)d_in[2];
  const float* conv_w = (const float*)d_in[3];
  const float* nq_w   = (const float*)d_in[4];
  const float* nk_w   = (const float*)d_in[5];
  const float* wq     = (const float*)d_in[6];
  const float* bq     = (const float*)d_in[7];
  const float* wk     = (const float*)d_in[8];
  const float* bk     = (const float*)d_in[9];
  float* out = (float*)d_out;

  const size_t N = (size_t)kB * kS * kC;   // 1,179,648
  short* vq   = (short*)d_ws;     // bf16 fragment-major V
  short* qp   = vq + N;           // bf16 [b][s][64], pre-scaled by 0.25*log2(e)
  short* kq   = qp + N;           // bf16 fragment-major K-proj
  short* wqb3 = kq + N;           // frag-major bf16
  short* wkb3 = wqb3 + 4096;
  short* wt3  = wkb3 + 4096;      // frag-major bf16 [72 slabs][512]

  prep_lite<<<1328, 256, 0, stream>>>(v, wq, wk, conv_w,
                                      vq, wqb3, wkb3, wt3, out);
  qk_gemm_t<<<576, 256, 0, stream>>>(q, k, wt3, wqb3, wkb3,
                                     nq_w, nk_w, bq, bk, qp, kq);
  attn_flash<<<1152, 256, 0, stream>>>(qp, kq, vq, out);
}